// Round 6
// baseline (235.438 us; speedup 1.0000x reference)
//
#include <hip/hip_runtime.h>
#include <stdint.h>

#define NB 32768
#define NPASS 4
#define FULL27 0x07FFFFFFu
#define NWORDS (NB * 27)   // 884736 packed words

// layout: per puzzle, 27 words; word (d*3+b) = digit d, band b (rows 3b..3b+2),
// bit (r*9+c) with r = local row 0..2, c = column 0..8.
// BOX k mask within band: 0x1C0E07 << 3k ; COL c: 0x40201 << c ; ROW r: 0x1FF << 9r
// Packed word w == bits of input floats [27w .. 27w+26] (flat order matches).

// ---------------- PACK: wave ballot -> 64 words per wave (validated r4) ----------------
__global__ __launch_bounds__(256)
void pack_kernel(const uint32_t* __restrict__ in, uint32_t* __restrict__ packed) {
    __shared__ uint32_t pool[4][56];
    const int lane = threadIdx.x & 63;
    const int wv = threadIdx.x >> 6;
    const size_t wordBase = (size_t)blockIdx.x * 256 + (size_t)wv * 64;
    const uint32_t* src = in + wordBase * 27;
    #pragma unroll
    for (int i = 0; i < 27; ++i) {
        uint32_t v = src[(size_t)i * 64 + lane];
        unsigned long long m = __ballot(v != 0u);
        if (lane == 0) {
            pool[wv][2 * i]     = (uint32_t)m;
            pool[wv][2 * i + 1] = (uint32_t)(m >> 32);
        }
    }
    __syncthreads();
    const int bit = lane * 27;
    const int di = bit >> 5;
    uint64_t both = (uint64_t)pool[wv][di] | ((uint64_t)pool[wv][di + 1] << 32);
    packed[wordBase + lane] = (uint32_t)(both >> (bit & 31)) & FULL27;
}

__device__ __forceinline__ uint32_t colfold(uint32_t w) {
    return (w | (w >> 9) | (w >> 18)) & 0x1FFu;
}
__device__ __forceinline__ uint32_t colmaj2(uint32_t w) {   // columns with >=2 bits in band
    return ((w & (w >> 9)) | ((w | (w >> 9)) & (w >> 18))) & 0x1FFu;
}

// ---------------- SOLVE: 3 lanes per puzzle, wave-internal shuffles ----------------
// Lane l: triple t = l/3 (puzzle), band = l%3. 21 puzzles/wave (lane 63 idle).
// All cross-band exchanges are __shfl within the triple: no LDS, no barriers,
// waves fully independent (r5 lesson: barriers at 1.5 waves/SIMD kill issue eff).
// Cross-band math identical to validated round-5 version.
__global__ __launch_bounds__(256, 1)
void solve_kernel(const uint32_t* __restrict__ pin, uint32_t* __restrict__ pout,
                  float* __restrict__ solved) {
    const int lane = threadIdx.x & 63;
    const int wv   = threadIdx.x >> 6;
    const int trip = lane / 3;              // 0..21 (21 = idle lane 63)
    const int band = lane - trip * 3;
    const int bo1 = band == 2 ? 0 : band + 1;
    const int bo2 = band == 0 ? 2 : band - 1;
    int sl1 = trip * 3 + bo1; if (sl1 > 63) sl1 = 63;   // partner lanes
    int sl2 = trip * 3 + bo2; if (sl2 > 63) sl2 = 63;
    const int p = blockIdx.x * 84 + wv * 21 + trip;
    const bool valid = (trip < 21) && (p < NB);
    const int pl = valid ? p : (NB - 1);    // clamped for loads

    uint32_t bd[9];
    {
        const uint32_t* src = pin + (size_t)pl * 27 + band;
        #pragma unroll
        for (int d = 0; d < 9; ++d) bd[d] = src[d * 3];
    }

    #pragma unroll 1
    for (int pass = 0; pass < NPASS; ++pass) {
        // ---------- filter 'box' (band-local) ----------
        {
            uint32_t on = 0, tw = 0, fo = 0;
            #pragma unroll
            for (int d = 0; d < 9; ++d) {
                uint32_t c = on & bd[d];
                on ^= bd[d]; fo |= tw & c; tw ^= c;
            }
            uint32_t ex1 = on & ~tw & ~fo;
            #pragma unroll
            for (int d = 0; d < 9; ++d) {
                uint32_t s = bd[d] & ex1;
                #pragma unroll
                for (int k = 0; k < 3; ++k) {
                    uint32_t bm = 0x1C0E07u << (3 * k);
                    uint32_t sm = s & bm;
                    uint32_t multi = sm & (sm - 1u);
                    uint32_t keep = (sm == 0u) ? 0xFFFFFFFFu : (~bm | (multi ? 0u : sm));
                    bd[d] &= keep;
                }
            }
        }

        // ---------- pointing 'h' (band-local) ----------
        #pragma unroll
        for (int d = 0; d < 9; ++d) {
            uint32_t w = bd[d];
            uint32_t t = (w | (w >> 1) | (w >> 2)) & 0x01249249u;
            uint32_t sum = (t & 0x1FFu) + ((t >> 9) & 0x1FFu) + ((t >> 18) & 0x1FFu);
            uint32_t single = sum & ~(sum >> 1) & 0x49u;
            uint32_t point = t & (single * 0x40201u);
            uint32_t clearm = 0;
            #pragma unroll
            for (int r = 0; r < 3; ++r) {
                uint32_t pr = (point >> (9 * r)) & 0x1FFu;
                uint32_t multi = pr & (pr - 1u);
                uint32_t segkeep = multi ? 0u : pr * 7u;
                uint32_t rc = pr ? ((0x1FFu & ~segkeep) << (9 * r)) : 0u;
                clearm |= rc;
            }
            bd[d] = w & ~clearm;
        }

        // ---------- pointing 'v' (cross-band via shuffle) ----------
        {
            uint32_t pnt[9];
            #pragma unroll
            for (int d = 0; d < 9; ++d) {
                uint32_t w = bd[d];
                uint32_t q = colfold(w);
                uint32_t u = (q & 0x49u) + ((q >> 1) & 0x49u) + ((q >> 2) & 0x49u);
                uint32_t single = u & ~(u >> 1) & 0x49u;
                pnt[d] = q & (single * 7u);
            }
            #pragma unroll
            for (int d = 0; d < 9; ++d) {
                uint32_t o = (uint32_t)__shfl((int)pnt[d], sl1, 64) |
                             (uint32_t)__shfl((int)pnt[d], sl2, 64);
                bd[d] &= ~(o * 0x40201u);
            }
        }

        // ---------- unique 'h' (band-local) ----------
        {
            uint32_t hid[9], has = 0;
            #pragma unroll
            for (int d = 0; d < 9; ++d) {
                uint32_t w = bd[d], h = 0;
                #pragma unroll
                for (int r = 0; r < 3; ++r) {
                    uint32_t x = w & (0x1FFu << (9 * r));
                    h |= (x & (x - 1u)) ? 0u : x;
                }
                hid[d] = h; has |= h;
            }
            #pragma unroll
            for (int d = 0; d < 9; ++d) bd[d] = (bd[d] & ~has) | hid[d];
        }

        // ---------- unique 'v' (cross-band via shuffle) ----------
        {
            uint32_t hid[9], has = 0;
            #pragma unroll
            for (int d = 0; d < 9; ++d) {
                uint32_t w = bd[d];
                uint32_t q0 = colfold(w), m0 = colmaj2(w);
                uint32_t ex = q0 | (m0 << 9);
                uint32_t ea = (uint32_t)__shfl((int)ex, sl1, 64);
                uint32_t eb = (uint32_t)__shfl((int)ex, sl2, 64);
                uint32_t qa = ea & 0x1FFu, ma = ea >> 9;
                uint32_t qb = eb & 0x1FFu, mb = eb >> 9;
                uint32_t ge2 = m0 | ma | mb | (q0 & qa) | (q0 & qb) | (qa & qb);
                uint32_t ex1c = (q0 | qa | qb) & ~ge2;   // column total count == 1
                hid[d] = w & ((ex1c & q0) * 0x40201u);
                has |= hid[d];
            }
            #pragma unroll
            for (int d = 0; d < 9; ++d) bd[d] = (bd[d] & ~has) | hid[d];
        }

        // ---------- unique 'box' (band-local) ----------
        {
            uint32_t hid[9], has = 0;
            #pragma unroll
            for (int d = 0; d < 9; ++d) {
                uint32_t w = bd[d], h = 0;
                #pragma unroll
                for (int k = 0; k < 3; ++k) {
                    uint32_t x = w & (0x1C0E07u << (3 * k));
                    h |= (x & (x - 1u)) ? 0u : x;
                }
                hid[d] = h; has |= h;
            }
            #pragma unroll
            for (int d = 0; d < 9; ++d) bd[d] = (bd[d] & ~has) | hid[d];
        }

        // ---------- doubles 'v' twice (cross-band via shuffle) ----------
        #pragma unroll 1
        for (int rep = 0; rep < 2; ++rep) {
            uint32_t on = 0, tw = 0, fo = 0;
            #pragma unroll
            for (int d = 0; d < 9; ++d) {
                uint32_t c = on & bd[d];
                on ^= bd[d]; fo |= tw & c; tw ^= c;
            }
            uint32_t ex2 = tw & ~on & ~fo;
            uint32_t Q[9], K[9];
            #pragma unroll
            for (int d = 0; d < 9; ++d) { Q[d] = bd[d] & ex2; K[d] = 0u; }
            #pragma unroll
            for (int d1 = 0; d1 < 9; ++d1)
                #pragma unroll
                for (int d2 = d1 + 1; d2 < 9; ++d2) {
                    uint32_t P = Q[d1] & Q[d2];
                    uint32_t f0 = colfold(P), g0 = colmaj2(P);
                    uint32_t ex = f0 | (g0 << 9);
                    uint32_t ea = (uint32_t)__shfl((int)ex, sl1, 64);
                    uint32_t eb = (uint32_t)__shfl((int)ex, sl2, 64);
                    uint32_t fa = ea & 0x1FFu, ga = ea >> 9;
                    uint32_t fb = eb & 0x1FFu, gb = eb >> 9;
                    // columns with >=2 exact-pair cells across the full column
                    uint32_t dup = g0 | ga | gb | (f0 & fa) | (f0 & fb) | (fa & fb);
                    uint32_t sK = P & (dup * 0x40201u);
                    K[d1] |= sK; K[d2] |= sK;
                }
            #pragma unroll
            for (int d = 0; d < 9; ++d) {
                uint32_t kc = colfold(K[d]);
                uint32_t cols = kc | (uint32_t)__shfl((int)kc, sl1, 64)
                                   | (uint32_t)__shfl((int)kc, sl2, 64);
                uint32_t em = cols * 0x40201u;
                bd[d] = (bd[d] & ~em) | K[d];
            }
        }

        // ---------- doubles 'box' (band-local) ----------
        {
            uint32_t on = 0, tw = 0, fo = 0;
            #pragma unroll
            for (int d = 0; d < 9; ++d) {
                uint32_t c = on & bd[d];
                on ^= bd[d]; fo |= tw & c; tw ^= c;
            }
            uint32_t ex2 = tw & ~on & ~fo;
            uint32_t Q[9], K[9];
            #pragma unroll
            for (int d = 0; d < 9; ++d) { Q[d] = bd[d] & ex2; K[d] = 0u; }
            #pragma unroll
            for (int d1 = 0; d1 < 9; ++d1)
                #pragma unroll
                for (int d2 = d1 + 1; d2 < 9; ++d2) {
                    uint32_t P = Q[d1] & Q[d2];
                    #pragma unroll
                    for (int k = 0; k < 3; ++k) {
                        uint32_t m = P & (0x1C0E07u << (3 * k));
                        uint32_t s = (m & (m - 1u)) ? m : 0u;
                        K[d1] |= s; K[d2] |= s;
                    }
                }
            #pragma unroll
            for (int d = 0; d < 9; ++d)
                #pragma unroll
                for (int k = 0; k < 3; ++k) {
                    uint32_t bm = 0x1C0E07u << (3 * k);
                    uint32_t t = K[d] & bm;
                    uint32_t mask = t ? (~bm | t) : 0xFFFFFFFFu;
                    bd[d] &= mask;
                }
        }
    } // passes

    // store packed result
    if (valid) {
        uint32_t* dst = pout + (size_t)p * 27 + band;
        #pragma unroll
        for (int d = 0; d < 9; ++d) dst[d * 3] = bd[d];
    }
    // solved flag: all cells count==1 in every band (AND across triple)
    {
        uint32_t on = 0, tw = 0, fo = 0;
        #pragma unroll
        for (int d = 0; d < 9; ++d) {
            uint32_t c = on & bd[d];
            on ^= bd[d]; fo |= tw & c; tw ^= c;
        }
        uint32_t okb = ((on & ~tw & ~fo) == FULL27) ? 1u : 0u;
        uint32_t all = okb & (uint32_t)__shfl((int)okb, sl1, 64)
                           & (uint32_t)__shfl((int)okb, sl2, 64);
        if (valid && band == 0) solved[p] = all ? 1.0f : 0.0f;
    }
}

// ---------------- EXPAND: 4 elements/thread, float4 stores (validated r4) ----------------
__global__ __launch_bounds__(256)
void expand_kernel(const uint32_t* __restrict__ packed, float4* __restrict__ out4) {
    int tid = blockIdx.x * blockDim.x + threadIdx.x;
    int base = tid * 4;
    int w0 = (int)((unsigned)base / 27u);
    int pos0 = base - w0 * 27;
    uint32_t a = packed[w0];
    int w1 = w0 + 1; if (w1 > NWORDS - 1) w1 = NWORDS - 1;
    uint32_t b = packed[w1];
    float r[4];
    #pragma unroll
    for (int k = 0; k < 4; ++k) {
        int pp = pos0 + k;
        uint32_t word = (pp < 27) ? a : b;
        int sh = (pp < 27) ? pp : pp - 27;
        r[k] = (float)((word >> sh) & 1u);
    }
    out4[tid] = make_float4(r[0], r[1], r[2], r[3]);
}

extern "C" void kernel_launch(void* const* d_in, const int* in_sizes, int n_in,
                              void* d_out, int out_size, void* d_ws, size_t ws_size,
                              hipStream_t stream) {
    const uint32_t* in = (const uint32_t*)d_in[0];   // float32 bits; nonzero <=> 1.0f
    float* out = (float*)d_out;
    float* solved = out + (size_t)NB * 729;
    uint32_t* packed = (uint32_t*)d_ws;              // NWORDS words = 3.54 MB

    pack_kernel<<<NWORDS / 256, 256, 0, stream>>>(in, packed);          // 3456 blocks
    // solve reads then overwrites its own 27 words: safe in-place
    // 84 puzzles per 256-thread block (21 per wave) -> ceil(32768/84) = 391 blocks
    solve_kernel<<<(NB + 83) / 84, 256, 0, stream>>>(packed, packed, solved);
    expand_kernel<<<(NB * 729 / 4) / 256, 256, 0, stream>>>(packed, (float4*)out); // 23328 blocks
}